// Round 14
// baseline (152.157 us; speedup 1.0000x reference)
//
#include <hip/hip_runtime.h>

typedef short bf16x8 __attribute__((ext_vector_type(8)));
typedef short bf16x4 __attribute__((ext_vector_type(4)));
typedef float floatx4 __attribute__((ext_vector_type(4)));

// fp32 -> bf16 round-to-nearest-even (finite inputs)
static __device__ __forceinline__ unsigned short f2bf(float f) {
  unsigned int x = __float_as_uint(f);
  x += 0x7fffu + ((x >> 16) & 1u);
  return (unsigned short)(x >> 16);
}

// KP (emb only, 64 blocks): emb -> eb bf16 + hn[k] = 0.5*||e_k||^2 ; block 0 zeroes loss.
__global__ __launch_bounds__(256) void k_prep(const float* __restrict__ emb,
                                              unsigned short* __restrict__ eb,
                                              float* __restrict__ hn,
                                              float* __restrict__ loss) {
  const int t = threadIdx.x, bid = blockIdx.x;
  if (bid == 0 && t == 0) *loss = 0.f;       // k_fullk (later dispatch) is the only reader/adder
  const int w = t >> 6, lane = t & 63;
  const int kb = (bid << 4) + (w << 2);
  for (int jj = 0; jj < 4; ++jj) {
    const int k = kb + jj;
    const float* er = emb + (k << 8);
    unsigned short* eo = eb + (k << 8);
    float ss = 0.f;
    for (int j = 0; j < 4; ++j) {
      const float v = er[j * 64 + lane];
      ss += v * v;
      eo[j * 64 + lane] = f2bf(v);
    }
    for (int off = 32; off >= 1; off >>= 1) ss += __shfl_xor(ss, off, 64);
    if (lane == 0) hn[k] = 0.5f * ss;
  }
}

// KB14 (4 blocks/CU): 1024 blocks x 256 thr x 32 rows, FULL 1024 codes/block.
// R13 post-mortem: R8 structure reproduced 112.2/112.5/112.4 with NO busy pipe (Mfma 9%,
// VALU 12%, HBM 11-16%) -- a latency floor at 8 waves/CU, where LDS (74KB -> 2 blocks/CU)
// was the binding occupancy constraint (VGPR 124 would allow 16 waves/CU).
// THIS VERSION halves the block: 32 rows, a[2][8] (64 VGPR), LDS 39,168B -> with
// __launch_bounds__(256,4) the compiler caps regs at 128 -> 4 blocks/CU = 16 waves/CU,
// doubling latency hiding for the cold x ingest and the E chain.
//  - es SINGLE-buffered (33.8KB): rows are wave-private and per-wave DS ops are in-order,
//    so tile kt's reads complete before tile kt+1's writes to the same rows. Barrier-free.
//  - tile2 (16.9KB) + tmp (16.4KB) + sel (32.9KB) all overlay the es region (phases disjoint).
//  - E traffic doubles (536MB) but eb (512KB) is per-XCD-L2 resident -> overlapped.
// Per-row MFMA values/order bit-identical to R13 -> indices unchanged; xn2 partial split
// changes (loss epsilon only; R5->R6 precedent left absmax at 0.001930237).
__global__ __launch_bounds__(256, 4) void k_fullk(const float* __restrict__ x,
                                                  const unsigned short* __restrict__ eb,
                                                  const float* __restrict__ hn,
                                                  const float* __restrict__ emb,
                                                  float* __restrict__ out,
                                                  float* __restrict__ loss) {
  // LDS map (bytes), total 39,168 (<=40,960 for 4 blocks/CU):
  //   [0, 33792)        es[64*264] shorts (E single buffer)
  //                       overlays: tile2[32*264] sh @0 (16,896); tmp[256*32] sh @16,896
  //                       (16,384; ends 33,280); sel[32][257] f32 @0 (32,896) at tail
  //   [33792, 37888)    hn_l[1024] f32 == xred2[4][256] f32 (prologue)
  //   [37888, 38400)    bvs[4][32] f32
  //   [38400, 38912)    bis[4][32] i32
  //   [38912, 39040)    idx_l[32] i32
  //   [39040, 39168)    xn2_l[32] f32
  __shared__ __align__(16) char smem[39168];
  unsigned short* es    = (unsigned short*)smem;
  unsigned short* tile2 = (unsigned short*)smem;
  unsigned short* tmp   = (unsigned short*)(smem + 16896);
  float* sel   = (float*)smem;
  float* hn_l  = (float*)(smem + 33792);
  float* xred2 = (float*)(smem + 33792);
  float* bvs   = (float*)(smem + 37888);
  int*   bis   = (int*)(smem + 38400);
  int*   idx_l = (int*)(smem + 38912);
  float* xn2_l = (float*)(smem + 39040);

  const int t = threadIdx.x;
  const int cq = t >> 6, lane = t & 63;        // wave = code-quarter
  const int r16 = lane & 15, quad = lane >> 4;
  const int n0 = blockIdx.x << 5;              // 32 rows/block
  const int b = n0 >> 10, hw0 = n0 & 1023;

  // ---- stage A: x float4 loads -> tmp[c][32hw] bf16, hw-split ss partials ----
  {
    const int hwq = t & 7, cidx = t >> 3;      // 8 x 4hw, 32 c per pass
    const float* xpb = x + ((size_t)b << 18) + hw0 + (hwq << 2);
    float ss0 = 0.f, ss1 = 0.f, ss2 = 0.f, ss3 = 0.f;
    for (int p = 0; p < 8; ++p) {
      const int c = (p << 5) + cidx;
      const float4 v = *(const float4*)(xpb + ((size_t)c << 10));
      ss0 += v.x * v.x; ss1 += v.y * v.y; ss2 += v.z * v.z; ss3 += v.w * v.w;
      bf16x4 u;
      u[0] = (short)f2bf(v.x); u[1] = (short)f2bf(v.y);
      u[2] = (short)f2bf(v.z); u[3] = (short)f2bf(v.w);
      *(bf16x4*)(&tmp[(c << 5) + (hwq << 2)]) = u;                  // tmp[c*32 + hw]
    }
    xred2[t] = ss0; xred2[256 + t] = ss1; xred2[512 + t] = ss2; xred2[768 + t] = ss3;
  }
  __syncthreads();                             // tmp + xred2 complete

  // ---- stage B: tmp[c][hw] -> tile2[hw][c] (b16 reads 2-lanes/dword) ----
  {
    const int row = t & 31, wv = t >> 5;       // wv 0..7
    for (int s = 0; s < 4; ++s) {
      const int c8 = wv + (s << 3);            // 32 c8-groups of 8 c
      bf16x8 u;
#pragma unroll
      for (int k = 0; k < 8; ++k) u[k] = (short)tmp[(((c8 << 3) + k) << 5) + row];
      *(bf16x8*)(&tile2[row * 264 + (c8 << 3)]) = u;
    }
  }
  // xn2 reduce: row r = t: j = r&3 (hw within quad), hwq = r>>2; cidx ascending
  if (t < 32) {
    const int j = t & 3, hwq = t >> 2;
    float s = 0.f;
    for (int cidx = 0; cidx < 32; ++cidx)
      s += xred2[j * 256 + (cidx << 3) + hwq];
    xn2_l[t] = s;
  }
  __syncthreads();                             // tile2 complete; xred2 consumed

  // A fragments from tile2: rows rg*16 + r16 (rg<2), c = quad*8 + ci*32
  bf16x8 a[2][8];
  for (int rg = 0; rg < 2; ++rg) {
    const unsigned short* tr = tile2 + ((rg << 4) + r16) * 264 + (quad << 3);
#pragma unroll
    for (int ci = 0; ci < 8; ++ci) a[rg][ci] = *(const bf16x8*)(tr + (ci << 5));
  }
  // hn quarter, WAVE-PRIVATE (overlays xred2 -- dead now; own-wave read only)
  for (int i = 0; i < 4; ++i)
    hn_l[(cq << 8) + (i << 6) + lane] = hn[(cq << 8) + (i << 6) + lane];
  __syncthreads();                             // tile2 consumed by all; es free

  // ---- E staging (wave-private rows 16w..16w+15; single buffer, barrier-free) ----
  const int g = t >> 5, c32 = (t & 31) << 3;
  bf16x8 pf[8];
#pragma unroll
  for (int i = 0; i < 8; ++i) {                // tile 0 loads
    const int r = (g << 3) + i;
    const int code = ((r >> 4) << 8) + (r & 15);
    pf[i] = *(const bf16x8*)(eb + ((size_t)code << 8) + c32);
  }
#pragma unroll
  for (int i = 0; i < 8; ++i) *(bf16x8*)(&es[((g << 3) + i) * 264 + c32]) = pf[i];
#pragma unroll
  for (int i = 0; i < 8; ++i) {                // tile 1 loads in flight
    const int r = (g << 3) + i;
    const int code = ((r >> 4) << 8) + 16 + (r & 15);
    pf[i] = *(const bf16x8*)(eb + ((size_t)code << 8) + c32);
  }

  float bv[2][4]; int bi[2][4];
  for (int rg = 0; rg < 2; ++rg)
    for (int r = 0; r < 4; ++r) { bv[rg][r] = -3.4e38f; bi[rg][r] = 0; }

  // ---- main loop: single es buffer; per-wave DS order gives read-before-overwrite ----
  for (int kt = 0; kt < 16; ++kt) {
    const unsigned short* esr = &es[((cq << 4) + r16) * 264 + (quad << 3)];
    floatx4 acc0 = {0.f,0.f,0.f,0.f}, acc1 = {0.f,0.f,0.f,0.f};
#pragma unroll
    for (int ci = 0; ci < 8; ++ci) {
      const bf16x8 bfr = *(const bf16x8*)(esr + (ci << 5));  // 1 read feeds 2 MFMAs
      acc0 = __builtin_amdgcn_mfma_f32_16x16x32_bf16(a[0][ci], bfr, acc0, 0, 0, 0);
      acc1 = __builtin_amdgcn_mfma_f32_16x16x32_bf16(a[1][ci], bfr, acc1, 0, 0, 0);
    }
    if (kt < 15)                               // write tile kt+1 over the same (own) rows
#pragma unroll
      for (int i = 0; i < 8; ++i) *(bf16x8*)(&es[((g << 3) + i) * 264 + c32]) = pf[i];
    if (kt < 14) {                             // issue loads of tile kt+2
#pragma unroll
      for (int i = 0; i < 8; ++i) {
        const int r = (g << 3) + i;
        const int code = ((r >> 4) << 8) + ((kt + 2) << 4) + (r & 15);
        pf[i] = *(const bf16x8*)(eb + ((size_t)code << 8) + c32);
      }
    }
    const int kglob = (cq << 8) + (kt << 4) + r16;
    const float h = hn_l[kglob];
#pragma unroll
    for (int r = 0; r < 4; ++r) {              // D: row = quad*4 + r, col(code) = r16
      float v;
      v = acc0[r] - h; if (v > bv[0][r]) { bv[0][r] = v; bi[0][r] = kglob; }
      v = acc1[r] - h; if (v > bv[1][r]) { bv[1][r] = v; bi[1][r] = kglob; }
    }
  }

  // reduce across the 16 code-columns (within each 16-lane group); ties -> lowest index
  for (int off = 8; off >= 1; off >>= 1)
    for (int rg = 0; rg < 2; ++rg)
      for (int r = 0; r < 4; ++r) {
        const float ov = __shfl_xor(bv[rg][r], off, 64);
        const int   oi = __shfl_xor(bi[rg][r], off, 64);
        if (ov > bv[rg][r] || (ov == bv[rg][r] && oi < bi[rg][r])) { bv[rg][r] = ov; bi[rg][r] = oi; }
      }
  if (r16 == 0) {
    for (int rg = 0; rg < 2; ++rg)
      for (int r = 0; r < 4; ++r) {
        const int row = (rg << 4) + (quad << 2) + r;      // 0..31
        bvs[(cq << 5) + row] = bv[rg][r];
        bis[(cq << 5) + row] = bi[rg][r];
      }
  }
  __syncthreads();                             // all quarters' bvs/bis visible

  // merge the 4 code-quarters (ascending q: strict > keeps lowest code on ties) + loss
  if (t < 32) {
    float vm = bvs[t]; int im = bis[t];
    for (int q = 1; q < 4; ++q) {
      const float v = bvs[(q << 5) + t];
      if (v > vm) { vm = v; im = bis[(q << 5) + t]; }
    }
    idx_l[t] = im;
    float lv = xn2_l[t] - 2.f * vm;            // = ||x_n - e_{im}||^2
    for (int off = 16; off >= 1; off >>= 1) lv += __shfl_xor(lv, off, 64);
    if (t == 0) atomicAdd(loss, lv * (1.25f / 8388608.0f));
  }
  __syncthreads();                             // es dead + idx_l ready; sel may overwrite

  // gather winning code rows into LDS (coalesced 256B loads from L2-resident emb)
  for (int i = 0; i < 8; ++i) {
    const int row = (cq << 3) + i;             // 32 rows over 4 waves
    const float* er = emb + ((size_t)idx_l[row] << 8);
    for (int j = 0; j < 4; ++j)
      sel[row * 257 + (j << 6) + lane] = er[(j << 6) + lane];
  }
  __syncthreads();
  // write out: float4 along hw (16B/lane)
  const int hwq = t & 7, cg = t >> 3;
  const size_t base = ((size_t)b << 18);       // b*256*1024
  for (int it = 0; it < 8; ++it) {
    const int c = (it << 5) + cg;
    float4 v;
    v.x = sel[(hwq * 4 + 0) * 257 + c];
    v.y = sel[(hwq * 4 + 1) * 257 + c];
    v.z = sel[(hwq * 4 + 2) * 257 + c];
    v.w = sel[(hwq * 4 + 3) * 257 + c];
    *(float4*)(out + base + ((size_t)c << 10) + hw0 + (hwq << 2)) = v;
  }
}

extern "C" void kernel_launch(void* const* d_in, const int* in_sizes, int n_in,
                              void* d_out, int out_size, void* d_ws, size_t ws_size,
                              hipStream_t stream) {
  const float* x   = (const float*)d_in[0];
  const float* emb = (const float*)d_in[1];
  float* out  = (float*)d_out;
  float* loss = out + 8388608;

  char* ws = (char*)d_ws;
  unsigned short* eb = (unsigned short*)(ws);              // 524,288 B
  float* hn = (float*)(ws + 524288);                       //   4,096 B

  k_prep<<<64, 256, 0, stream>>>(emb, eb, hn, loss);
  k_fullk<<<1024, 256, 0, stream>>>(x, eb, hn, emb, out, loss);
}

// Round 15
// 121.103 us; speedup vs baseline: 1.2564x; 1.2564x over previous
//
#include <hip/hip_runtime.h>

typedef short bf16x8 __attribute__((ext_vector_type(8)));
typedef short bf16x4 __attribute__((ext_vector_type(4)));
typedef float floatx4 __attribute__((ext_vector_type(4)));

// fp32 -> bf16 round-to-nearest-even (finite inputs)
static __device__ __forceinline__ unsigned short f2bf(float f) {
  unsigned int x = __float_as_uint(f);
  x += 0x7fffu + ((x >> 16) & 1u);
  return (unsigned short)(x >> 16);
}

// KP (emb only, 64 blocks): emb -> eb bf16 + hn[k] = 0.5*||e_k||^2 ; block 0 zeroes loss.
__global__ __launch_bounds__(256) void k_prep(const float* __restrict__ emb,
                                              unsigned short* __restrict__ eb,
                                              float* __restrict__ hn,
                                              float* __restrict__ loss) {
  const int t = threadIdx.x, bid = blockIdx.x;
  if (bid == 0 && t == 0) *loss = 0.f;       // k_fullk (later dispatch) is the only reader/adder
  const int w = t >> 6, lane = t & 63;
  const int kb = (bid << 4) + (w << 2);
  for (int jj = 0; jj < 4; ++jj) {
    const int k = kb + jj;
    const float* er = emb + (k << 8);
    unsigned short* eo = eb + (k << 8);
    float ss = 0.f;
    for (int j = 0; j < 4; ++j) {
      const float v = er[j * 64 + lane];
      ss += v * v;
      eo[j * 64 + lane] = f2bf(v);
    }
    for (int off = 32; off >= 1; off >>= 1) ss += __shfl_xor(ss, off, 64);
    if (lane == 0) hn[k] = 0.5f * ss;
  }
}

// KB15 (KB14 minus the VGPR-strangling hint): 1024 blocks x 256 thr x 32 rows, full 1024
// codes/block, LDS 39,168B -> 4 blocks/CU by LDS.
// R14 post-mortem: __launch_bounds__(256,4) made the compiler allocate only 64 VGPRs
// (body needs ~110) -> +55MB scratch spill, 80-93us. BUT OccupancyPercent rose 20->34.5,
// proving the occupancy mechanism engages. This round: plain __launch_bounds__(256) --
// compiler allocates what the body needs (<=128), LDS still caps at 4 blocks/CU, same
// 16 waves/CU target WITHOUT the spill. Structure otherwise identical to R14:
//  - es SINGLE-buffered (33.8KB), wave-private rows, barrier-free main loop
//  - tile2/tmp/sel overlay the es region (phases disjoint)
//  - per-row MFMA values/order bit-identical to R13 -> indices unchanged.
__global__ __launch_bounds__(256) void k_fullk(const float* __restrict__ x,
                                               const unsigned short* __restrict__ eb,
                                               const float* __restrict__ hn,
                                               const float* __restrict__ emb,
                                               float* __restrict__ out,
                                               float* __restrict__ loss) {
  // LDS map (bytes), total 39,168:
  //   [0, 33792)        es[64*264] shorts (E single buffer)
  //                       overlays: tile2[32*264] sh @0 (16,896); tmp[256*32] sh @16,896
  //                       (16,384; ends 33,280); sel[32][257] f32 @0 (32,896) at tail
  //   [33792, 37888)    hn_l[1024] f32 == xred2[4][256] f32 (prologue)
  //   [37888, 38400)    bvs[4][32] f32
  //   [38400, 38912)    bis[4][32] i32
  //   [38912, 39040)    idx_l[32] i32
  //   [39040, 39168)    xn2_l[32] f32
  __shared__ __align__(16) char smem[39168];
  unsigned short* es    = (unsigned short*)smem;
  unsigned short* tile2 = (unsigned short*)smem;
  unsigned short* tmp   = (unsigned short*)(smem + 16896);
  float* sel   = (float*)smem;
  float* hn_l  = (float*)(smem + 33792);
  float* xred2 = (float*)(smem + 33792);
  float* bvs   = (float*)(smem + 37888);
  int*   bis   = (int*)(smem + 38400);
  int*   idx_l = (int*)(smem + 38912);
  float* xn2_l = (float*)(smem + 39040);

  const int t = threadIdx.x;
  const int cq = t >> 6, lane = t & 63;        // wave = code-quarter
  const int r16 = lane & 15, quad = lane >> 4;
  const int n0 = blockIdx.x << 5;              // 32 rows/block
  const int b = n0 >> 10, hw0 = n0 & 1023;

  // ---- stage A: x float4 loads -> tmp[c][32hw] bf16, hw-split ss partials ----
  {
    const int hwq = t & 7, cidx = t >> 3;      // 8 x 4hw, 32 c per pass
    const float* xpb = x + ((size_t)b << 18) + hw0 + (hwq << 2);
    float ss0 = 0.f, ss1 = 0.f, ss2 = 0.f, ss3 = 0.f;
    for (int p = 0; p < 8; ++p) {
      const int c = (p << 5) + cidx;
      const float4 v = *(const float4*)(xpb + ((size_t)c << 10));
      ss0 += v.x * v.x; ss1 += v.y * v.y; ss2 += v.z * v.z; ss3 += v.w * v.w;
      bf16x4 u;
      u[0] = (short)f2bf(v.x); u[1] = (short)f2bf(v.y);
      u[2] = (short)f2bf(v.z); u[3] = (short)f2bf(v.w);
      *(bf16x4*)(&tmp[(c << 5) + (hwq << 2)]) = u;                  // tmp[c*32 + hw]
    }
    xred2[t] = ss0; xred2[256 + t] = ss1; xred2[512 + t] = ss2; xred2[768 + t] = ss3;
  }
  __syncthreads();                             // tmp + xred2 complete

  // ---- stage B: tmp[c][hw] -> tile2[hw][c] (b16 reads 2-lanes/dword) ----
  {
    const int row = t & 31, wv = t >> 5;       // wv 0..7
    for (int s = 0; s < 4; ++s) {
      const int c8 = wv + (s << 3);            // 32 c8-groups of 8 c
      bf16x8 u;
#pragma unroll
      for (int k = 0; k < 8; ++k) u[k] = (short)tmp[(((c8 << 3) + k) << 5) + row];
      *(bf16x8*)(&tile2[row * 264 + (c8 << 3)]) = u;
    }
  }
  // xn2 reduce: row r = t: j = r&3 (hw within quad), hwq = r>>2; cidx ascending
  if (t < 32) {
    const int j = t & 3, hwq = t >> 2;
    float s = 0.f;
    for (int cidx = 0; cidx < 32; ++cidx)
      s += xred2[j * 256 + (cidx << 3) + hwq];
    xn2_l[t] = s;
  }
  __syncthreads();                             // tile2 complete; xred2 consumed

  // A fragments from tile2: rows rg*16 + r16 (rg<2), c = quad*8 + ci*32
  bf16x8 a[2][8];
  for (int rg = 0; rg < 2; ++rg) {
    const unsigned short* tr = tile2 + ((rg << 4) + r16) * 264 + (quad << 3);
#pragma unroll
    for (int ci = 0; ci < 8; ++ci) a[rg][ci] = *(const bf16x8*)(tr + (ci << 5));
  }
  // hn quarter, WAVE-PRIVATE (overlays xred2 -- dead now; own-wave read only)
  for (int i = 0; i < 4; ++i)
    hn_l[(cq << 8) + (i << 6) + lane] = hn[(cq << 8) + (i << 6) + lane];
  __syncthreads();                             // tile2 consumed by all; es free

  // ---- E staging (wave-private rows 16w..16w+15; single buffer, barrier-free) ----
  const int g = t >> 5, c32 = (t & 31) << 3;
  bf16x8 pf[8];
#pragma unroll
  for (int i = 0; i < 8; ++i) {                // tile 0 loads
    const int r = (g << 3) + i;
    const int code = ((r >> 4) << 8) + (r & 15);
    pf[i] = *(const bf16x8*)(eb + ((size_t)code << 8) + c32);
  }
#pragma unroll
  for (int i = 0; i < 8; ++i) *(bf16x8*)(&es[((g << 3) + i) * 264 + c32]) = pf[i];
#pragma unroll
  for (int i = 0; i < 8; ++i) {                // tile 1 loads in flight
    const int r = (g << 3) + i;
    const int code = ((r >> 4) << 8) + 16 + (r & 15);
    pf[i] = *(const bf16x8*)(eb + ((size_t)code << 8) + c32);
  }

  float bv[2][4]; int bi[2][4];
  for (int rg = 0; rg < 2; ++rg)
    for (int r = 0; r < 4; ++r) { bv[rg][r] = -3.4e38f; bi[rg][r] = 0; }

  // ---- main loop: single es buffer; per-wave DS order gives read-before-overwrite ----
  for (int kt = 0; kt < 16; ++kt) {
    const unsigned short* esr = &es[((cq << 4) + r16) * 264 + (quad << 3)];
    floatx4 acc0 = {0.f,0.f,0.f,0.f}, acc1 = {0.f,0.f,0.f,0.f};
#pragma unroll
    for (int ci = 0; ci < 8; ++ci) {
      const bf16x8 bfr = *(const bf16x8*)(esr + (ci << 5));  // 1 read feeds 2 MFMAs
      acc0 = __builtin_amdgcn_mfma_f32_16x16x32_bf16(a[0][ci], bfr, acc0, 0, 0, 0);
      acc1 = __builtin_amdgcn_mfma_f32_16x16x32_bf16(a[1][ci], bfr, acc1, 0, 0, 0);
    }
    if (kt < 15)                               // write tile kt+1 over the same (own) rows
#pragma unroll
      for (int i = 0; i < 8; ++i) *(bf16x8*)(&es[((g << 3) + i) * 264 + c32]) = pf[i];
    if (kt < 14) {                             // issue loads of tile kt+2
#pragma unroll
      for (int i = 0; i < 8; ++i) {
        const int r = (g << 3) + i;
        const int code = ((r >> 4) << 8) + ((kt + 2) << 4) + (r & 15);
        pf[i] = *(const bf16x8*)(eb + ((size_t)code << 8) + c32);
      }
    }
    const int kglob = (cq << 8) + (kt << 4) + r16;
    const float h = hn_l[kglob];
#pragma unroll
    for (int r = 0; r < 4; ++r) {              // D: row = quad*4 + r, col(code) = r16
      float v;
      v = acc0[r] - h; if (v > bv[0][r]) { bv[0][r] = v; bi[0][r] = kglob; }
      v = acc1[r] - h; if (v > bv[1][r]) { bv[1][r] = v; bi[1][r] = kglob; }
    }
  }

  // reduce across the 16 code-columns (within each 16-lane group); ties -> lowest index
  for (int off = 8; off >= 1; off >>= 1)
    for (int rg = 0; rg < 2; ++rg)
      for (int r = 0; r < 4; ++r) {
        const float ov = __shfl_xor(bv[rg][r], off, 64);
        const int   oi = __shfl_xor(bi[rg][r], off, 64);
        if (ov > bv[rg][r] || (ov == bv[rg][r] && oi < bi[rg][r])) { bv[rg][r] = ov; bi[rg][r] = oi; }
      }
  if (r16 == 0) {
    for (int rg = 0; rg < 2; ++rg)
      for (int r = 0; r < 4; ++r) {
        const int row = (rg << 4) + (quad << 2) + r;      // 0..31
        bvs[(cq << 5) + row] = bv[rg][r];
        bis[(cq << 5) + row] = bi[rg][r];
      }
  }
  __syncthreads();                             // all quarters' bvs/bis visible

  // merge the 4 code-quarters (ascending q: strict > keeps lowest code on ties) + loss
  if (t < 32) {
    float vm = bvs[t]; int im = bis[t];
    for (int q = 1; q < 4; ++q) {
      const float v = bvs[(q << 5) + t];
      if (v > vm) { vm = v; im = bis[(q << 5) + t]; }
    }
    idx_l[t] = im;
    float lv = xn2_l[t] - 2.f * vm;            // = ||x_n - e_{im}||^2
    for (int off = 16; off >= 1; off >>= 1) lv += __shfl_xor(lv, off, 64);
    if (t == 0) atomicAdd(loss, lv * (1.25f / 8388608.0f));
  }
  __syncthreads();                             // es dead + idx_l ready; sel may overwrite

  // gather winning code rows into LDS (coalesced 256B loads from L2-resident emb)
  for (int i = 0; i < 8; ++i) {
    const int row = (cq << 3) + i;             // 32 rows over 4 waves
    const float* er = emb + ((size_t)idx_l[row] << 8);
    for (int j = 0; j < 4; ++j)
      sel[row * 257 + (j << 6) + lane] = er[(j << 6) + lane];
  }
  __syncthreads();
  // write out: float4 along hw (16B/lane)
  const int hwq = t & 7, cg = t >> 3;
  const size_t base = ((size_t)b << 18);       // b*256*1024
  for (int it = 0; it < 8; ++it) {
    const int c = (it << 5) + cg;
    float4 v;
    v.x = sel[(hwq * 4 + 0) * 257 + c];
    v.y = sel[(hwq * 4 + 1) * 257 + c];
    v.z = sel[(hwq * 4 + 2) * 257 + c];
    v.w = sel[(hwq * 4 + 3) * 257 + c];
    *(float4*)(out + base + ((size_t)c << 10) + hw0 + (hwq << 2)) = v;
  }
}

extern "C" void kernel_launch(void* const* d_in, const int* in_sizes, int n_in,
                              void* d_out, int out_size, void* d_ws, size_t ws_size,
                              hipStream_t stream) {
  const float* x   = (const float*)d_in[0];
  const float* emb = (const float*)d_in[1];
  float* out  = (float*)d_out;
  float* loss = out + 8388608;

  char* ws = (char*)d_ws;
  unsigned short* eb = (unsigned short*)(ws);              // 524,288 B
  float* hn = (float*)(ws + 524288);                       //   4,096 B

  k_prep<<<64, 256, 0, stream>>>(emb, eb, hn, loss);
  k_fullk<<<1024, 256, 0, stream>>>(x, eb, hn, emb, out, loss);
}